// Round 1
// baseline (235.523 us; speedup 1.0000x reference)
//
#include <hip/hip_runtime.h>

#define B_DIM 4096
#define L_DIM 4096
#define ROWS 16            // rows per block (one compute lane per row)
#define TCH 256            // time-chunk length (floats per row per chunk)
#define NCH (L_DIM / TCH)  // 16 chunks
#define LDS_STRIDE 260     // 256 + 4 pad: keeps 16B alignment, spreads banks

// One block = 1 wave (64 threads). Lanes 0..15 each own one row's sequential
// LIF chain; all 64 lanes cooperate on global->LDS staging (coalesced 1KB
// per instruction). Double-buffered LDS chunks: loads for chunk c+1 are
// issued (into VGPRs) before computing chunk c, ds_written after.
__global__ __launch_bounds__(64) void lif_kernel(const float* __restrict__ I,
                                                 float* __restrict__ out) {
    __shared__ __align__(16) float lds[2][ROWS * LDS_STRIDE];
    const int lane = threadIdx.x;
    const int rowBase = blockIdx.x * ROWS;

    // ---- stage chunk 0 into buffer 0 ----
    float4 stage[ROWS];
#pragma unroll
    for (int i = 0; i < ROWS; ++i)
        stage[i] = *(const float4*)(I + (size_t)(rowBase + i) * L_DIM + lane * 4);
#pragma unroll
    for (int i = 0; i < ROWS; ++i)
        *(float4*)&lds[0][i * LDS_STRIDE + lane * 4] = stage[i];

    const int r = lane;  // row index within block (valid when lane < ROWS)
    float v = 0.f;       // membrane potential
    float cnt = 0.f;     // spike count C
    float seen = 0.f;    // 1 once first spike happened
    float accS = 0.f;    // sum over t of cnt_after_t  -> tsum = L*C - accS
    float accF = 0.f;    // sum over t of seen_t       -> first = L - accF
    const float c = 0.05f;  // RN(1/20)

    float* srow = out + (size_t)(rowBase + (r < ROWS ? r : 0)) * L_DIM;

    // Exact IEEE-f32 step: v = (v - RN(v/20)) + I; spike = v>=1; reset.
    // RN(v/20) via Markstein: q0=v*c; rr=fma(-20,q0,v); q=fma(rr,c,q0).
#define LIF_STEP(IIN, SOUT)                        \
    {                                              \
        float q0 = v * c;                          \
        float rr = fmaf(-20.0f, q0, v);            \
        float q = fmaf(rr, c, q0);                 \
        float w = v - q;                           \
        float u = w + (IIN);                       \
        bool sp = (u >= 1.0f);                     \
        v = sp ? 0.0f : u;                         \
        float sf = sp ? 1.0f : 0.0f;               \
        cnt += sf;                                 \
        seen = fmaxf(seen, sf);                    \
        accS += cnt;                               \
        accF += seen;                              \
        (SOUT) = sf;                               \
    }

    for (int ch = 0; ch < NCH; ++ch) {
        const float* buf = lds[ch & 1];

        // Issue next chunk's global loads now; first use (ds_write) is after
        // the ~7000-cycle compute loop, so HBM latency is fully hidden.
        if (ch + 1 < NCH) {
#pragma unroll
            for (int i = 0; i < ROWS; ++i)
                stage[i] = *(const float4*)(I + (size_t)(rowBase + i) * L_DIM +
                                            (ch + 1) * TCH + lane * 4);
        }

        if (lane < ROWS) {
            const float* lrow = buf + r * LDS_STRIDE;
            float* sdst = srow + ch * TCH;
#pragma unroll 4
            for (int tt = 0; tt < TCH; tt += 4) {
                const float4 iv = *(const float4*)(lrow + tt);
                float4 sv;
                LIF_STEP(iv.x, sv.x);
                LIF_STEP(iv.y, sv.y);
                LIF_STEP(iv.z, sv.z);
                LIF_STEP(iv.w, sv.w);
                *(float4*)(sdst + tt) = sv;  // packed 0/1 spike output
            }
        }

        if (ch + 1 < NCH) {
            float* nbuf = lds[(ch + 1) & 1];
#pragma unroll
            for (int i = 0; i < ROWS; ++i)
                *(float4*)&nbuf[i * LDS_STRIDE + lane * 4] = stage[i];
        }
        // single-wave block: DS pipe is in-order per wave, no barrier needed
    }

    if (lane < ROWS) {
        const int row = rowBase + r;
        const float C = cnt;
        // tsum = L*C - sum_t cnt_t ; exact (integers < 2^24)
        const float tsum = fmaf((float)L_DIM, C, -accS);
        const float first = (float)L_DIM - accF;  // L if never spiked
        const float soft = tsum / (C + 1e-6f);
        out[(size_t)B_DIM * L_DIM + row] = first;                 // hard_latency
        out[(size_t)B_DIM * L_DIM + B_DIM + row] = soft;          // soft_latency
    }
#undef LIF_STEP
}

extern "C" void kernel_launch(void* const* d_in, const int* in_sizes, int n_in,
                              void* d_out, int out_size, void* d_ws, size_t ws_size,
                              hipStream_t stream) {
    const float* I = (const float*)d_in[0];
    float* out = (float*)d_out;
    (void)in_sizes; (void)n_in; (void)out_size; (void)d_ws; (void)ws_size;
    lif_kernel<<<B_DIM / ROWS, 64, 0, stream>>>(I, out);
}

// Round 3
// 233.563 us; speedup vs baseline: 1.0084x; 1.0084x over previous
//
#include <hip/hip_runtime.h>

#define B_DIM 4096
#define L_DIM 4096
#define ROWS 16            // rows per block, one compute lane per row
#define TCH 128            // time-chunk length (floats per row per chunk)
#define NCH (L_DIM / TCH)  // 32 chunks
#define TCF4 (TCH / 4)     // 32 float4 per row per chunk
#define STRIDE_F4 (TCF4 + 1)  // 33 (odd) -> bank spread
#define BUF_F4 (ROWS * STRIDE_F4)
#define SREGS 8            // (ROWS*TCF4)/64 staging float4 per lane per chunk

// One block = 1 wave. Lanes 0..15 each own one row's serial LIF chain; all 64
// lanes cooperate on coalesced global->LDS staging (double-buffered).
// Per chunk: (1) issue next chunk's global loads into S regs, (2) bulk
// ds_read this chunk into R regs (one ~120cyc bubble per chunk), (3) 128
// steps of 6-dep-op chain, (4) ds_write S (vmcnt long since drained).
__global__ __launch_bounds__(64, 1) void lif_kernel(const float* __restrict__ I,
                                                    float* __restrict__ out) {
    __shared__ __align__(16) float4 lds[2 * BUF_F4];
    const int lane = threadIdx.x;
    const int rowBase = blockIdx.x * ROWS;

    // staging map: iter i -> (row srow + 4*(i&3), f4-col scol + 16*(i>>2))
    const int srow = lane >> 4;   // 0..3
    const int scol = lane & 15;   // 0..15
    const float* gbase = I + (size_t)(rowBase + srow) * L_DIM + scol * 4;

    float4 S[SREGS];
    // ---- prologue: stage chunk 0 into buffer 0 ----
#pragma unroll
    for (int i = 0; i < SREGS; ++i)
        S[i] = *(const float4*)(gbase + (size_t)(i & 3) * 4 * L_DIM + (i >> 2) * 64);
#pragma unroll
    for (int i = 0; i < SREGS; ++i)
        lds[(4 * (i & 3) + srow) * STRIDE_F4 + scol + 16 * (i >> 2)] = S[i];

    float u = 0.f, cnt = 0.f, seen = 0.f, accS = 0.f, accF = 0.f;
    bool sp = false;
    const float cdiv = 0.05f;  // RN(1/20)

    float* orow = out + (size_t)(rowBase + (lane < ROWS ? lane : 0)) * L_DIM;

    // Exact IEEE step, compare off the critical path:
    //   q = RN(u/20) via Markstein (q0=u*c; rr=fma(-20,q0,u); q=fma(rr,c,q0))
    //   a = u - q; b = a + I'; u' = sp_prev ? I' : b   (reset path == I' exactly)
#define LIF_STEP(IIN, SOUT)                          \
    {                                                \
        float q0 = u * cdiv;                         \
        float rr = fmaf(-20.0f, q0, u);              \
        float q  = fmaf(rr, cdiv, q0);               \
        float a  = u - q;                            \
        float b  = a + (IIN);                        \
        u = sp ? (IIN) : b;                          \
        sp = (u >= 1.0f);                            \
        float sf = sp ? 1.0f : 0.0f;                 \
        cnt += sf;                                   \
        seen = fmaxf(seen, sf);                      \
        accS += cnt;                                 \
        accF += seen;                                \
        (SOUT) = sf;                                 \
    }

    for (int c = 0; c < NCH; ++c) {
        // (1) issue next chunk's global loads now; vmcnt drains during compute
        if (c + 1 < NCH) {
            const float* g = gbase + (size_t)(c + 1) * TCH;
#pragma unroll
            for (int i = 0; i < SREGS; ++i)
                S[i] = *(const float4*)(g + (size_t)(i & 3) * 4 * L_DIM + (i >> 2) * 64);
        }

        // (2) bulk LDS->register read of the whole chunk (pipelined lgkmcnt)
        const float4* buf = lds + (c & 1) * BUF_F4 + (lane < ROWS ? lane : 0) * STRIDE_F4;
        float4 R[TCF4];
#pragma unroll
        for (int j = 0; j < TCF4; ++j) R[j] = buf[j];

        // (3) compute 128 steps, packed float4 spike stores
        if (lane < ROWS) {
            float* sdst = orow + c * TCH;
#pragma unroll
            for (int g4 = 0; g4 < TCF4; ++g4) {
                float4 iv = R[g4];
                float4 sv;
                LIF_STEP(iv.x, sv.x)
                LIF_STEP(iv.y, sv.y)
                LIF_STEP(iv.z, sv.z)
                LIF_STEP(iv.w, sv.w)
                *(float4*)(sdst + g4 * 4) = sv;
            }
        }

        // (4) stage next chunk into the other buffer (single-wave: DS in-order)
        if (c + 1 < NCH) {
            float4* nbuf = lds + ((c + 1) & 1) * BUF_F4;
#pragma unroll
            for (int i = 0; i < SREGS; ++i)
                nbuf[(4 * (i & 3) + srow) * STRIDE_F4 + scol + 16 * (i >> 2)] = S[i];
        }
    }

    if (lane < ROWS) {
        const int row = rowBase + lane;
        const float C = cnt;
        const float tsum = fmaf((float)L_DIM, C, -accS);  // = sum_t t*s_t, exact ints
        const float first = (float)L_DIM - accF;          // L if never spiked
        const float soft = tsum / (C + 1e-6f);
        out[(size_t)B_DIM * L_DIM + row] = first;               // hard_latency
        out[(size_t)B_DIM * L_DIM + B_DIM + row] = soft;        // soft_latency
    }
#undef LIF_STEP
}

extern "C" void kernel_launch(void* const* d_in, const int* in_sizes, int n_in,
                              void* d_out, int out_size, void* d_ws, size_t ws_size,
                              hipStream_t stream) {
    const float* I = (const float*)d_in[0];
    float* out = (float*)d_out;
    (void)in_sizes; (void)n_in; (void)out_size; (void)d_ws; (void)ws_size;
    lif_kernel<<<B_DIM / ROWS, 64, 0, stream>>>(I, out);
}